// Round 11
// baseline (373.916 us; speedup 1.0000x reference)
//
#include <hip/hip_runtime.h>
#include <hip/hip_fp16.h>
#include <float.h>

#define MKEY 256        // K (key size)
#define NMEM 100000     // memory rows
#define NPAD 100096     // 782 * 128
#define NQ   2048       // queries
#define BM 128
#define BN 128
#define NTILES 782      // NPAD / BN : 128-row blocks
#define BLKPAD 800      // padded row stride for bmaxQ
#define GRID (128 * 98) // XCD-clustered id space; ntile>=782 early-exits
#define KB16 (NPAD / 16)       // 6256 convert key-blocks (16 rows each)
#define QS (127.0f / 6.0f)     // i8 quant scale (data ~N(0,1), clamp at 6 sigma)
#define SS2 ((6.0f / 127.0f) * (6.0f / 127.0f))  // dequant: dot_f = dot_i8 * SS2
#define GDELTA 0.04f    // group-code quantum (ub = bmax - code*GDELTA >= gmax)
#define GINVD  25.0f

typedef int i32x4 __attribute__((ext_vector_type(4)));

__device__ inline void gll16(const void* g, void* l) {
  __builtin_amdgcn_global_load_lds(
      (const __attribute__((address_space(1))) unsigned*)g,
      (__attribute__((address_space(3))) unsigned*)l, 16, 0, 0);
}

__device__ inline int pack_i8x4(float4 v) {
  int c0 = max(-127, min(127, __float2int_rn(v.x * QS)));
  int c1 = max(-127, min(127, __float2int_rn(v.y * QS)));
  int c2 = max(-127, min(127, __float2int_rn(v.z * QS)));
  int c3 = max(-127, min(127, __float2int_rn(v.w * QS)));
  return (c0 & 255) | ((c1 & 255) << 8) | ((c2 & 255) << 16) | ((c3 & 255) << 24);
}

// signed 4x i8 dot; HW v_dot4 when available (i32 result exact either way)
__device__ inline int dot4i8(int a, int b, int s) {
#if __has_builtin(__builtin_amdgcn_sdot4)
  return __builtin_amdgcn_sdot4(a, b, s, false);
#else
#pragma unroll
  for (int k = 0; k < 4; ++k) {
    const int av = (a << (24 - 8 * k)) >> 24;
    const int bv = (b << (24 - 8 * k)) >> 24;
    s += av * bv;
  }
  return s;
#endif
}

// merged convert: keys fp32 -> i8 + inv key norm, 16 lanes per row.
// (~37 us: at the HBM floor for 102 MB key reads + 26 MB writes.)
__global__ void convert(const float* __restrict__ q, const float* __restrict__ mem,
                        int* __restrict__ qi, int* __restrict__ ki,
                        float* __restrict__ rkn) {
  const int b = blockIdx.x, t = threadIdx.x;
  if (b >= KB16) {
    const int i = (b - KB16) * 256 + t;   // int4-group index
    const float4 v = *(const float4*)&q[(size_t)i * 4];
    qi[i] = pack_i8x4(v);
    return;
  }
  const int row = b * 16 + (t >> 4);
  const int c = t & 15;                   // 16-float chunk of the row
  if (row < NMEM) {
    const float* src = &mem[(size_t)row * 512 + c * 16];
    const float4 v0 = *(const float4*)&src[0];
    const float4 v1 = *(const float4*)&src[4];
    const float4 v2 = *(const float4*)&src[8];
    const float4 v3 = *(const float4*)&src[12];
    float ss = v0.x * v0.x + v0.y * v0.y + v0.z * v0.z + v0.w * v0.w +
               v1.x * v1.x + v1.y * v1.y + v1.z * v1.z + v1.w * v1.w +
               v2.x * v2.x + v2.y * v2.y + v2.z * v2.z + v2.w * v2.w +
               v3.x * v3.x + v3.y * v3.y + v3.z * v3.z + v3.w * v3.w;
#pragma unroll
    for (int off = 8; off >= 1; off >>= 1) ss += __shfl_xor(ss, off, 64);
    int4 pk;
    pk.x = pack_i8x4(v0); pk.y = pack_i8x4(v1);
    pk.z = pack_i8x4(v2); pk.w = pack_i8x4(v3);
    *(int4*)&ki[(size_t)row * 64 + c * 4] = pk;
    if (c == 0) rkn[row] = 1.0f / sqrtf(fmaxf(ss, 1e-30f));
  } else {
    *(int4*)&ki[(size_t)row * 64 + c * 4] = make_int4(0, 0, 0, 0);
    if (c == 0) rkn[row] = 0.f;
  }
}

// Pass 1: i8 screening GEMM (mfma_i32_16x16x64_i8). 128x128 tile, 4 waves,
// 4 blocks/CU, BK=64 double-buffered 2-phase pipeline (R8/R10-proven).
// SWAPPED OPERANDS: mfma(keys, queries) so D rows = keys (4*q16+r, in-register
// across r) and D cols = queries (l16). The 16-key group-max then costs
// 3 reg-fmax + 2 shfl_xor per fragment instead of a 128-KB LDS round-trip
// (R8 epilogue) or 576 DPP ops (R9). Epilogue LDS: one 4-KB cg table, 1 barrier.
//   bcode8[nt*NQ + qid] : u64 of 8 per-group codes; ub_g = bmax - code*GDELTA
//   bmaxB [nt*NQ + qid] : per-128-key-block max
__global__ __launch_bounds__(256, 4) void gemm_screen(
    const int* __restrict__ qi, const int* __restrict__ ki,
    const float* __restrict__ rkn,
    unsigned long long* __restrict__ bcode8, float* __restrict__ bmaxB) {
  // bufA[p] (queries) at p*8192; bufB[p] (keys) at 16384+p*8192.
  // Epilogue overlays cg[8][128] (4 KB) on dead bufA after the final barrier.
  __shared__ __align__(128) char smem[32768];

  const int id = blockIdx.x;
  const int mtile = (id >> 3) & 15;
  const int ntile = (id & 7) + 8 * (id >> 7);
  if (ntile >= NTILES) return;

  const int t = threadIdx.x;
  const int w = t >> 6;
  const int lane = t & 63;
  const int wr = w >> 1, wc = w & 1;     // wr: key strip (A/M), wc: query strip (B/N)
  const int q16 = lane >> 4, l16 = lane & 15;

  // staging: waves 0,1 -> queries (bufA halves); waves 2,3 -> keys (bufB).
  // phys chunk (lane&3) at row holds global chunk (lane&3)^((row>>1)&3);
  // row>>1 within the 8-aligned span reduces to lane>>3. (R10-proven.)
  const int swz64 = ((lane & 3) ^ ((lane >> 3) & 3)) * 16;
  int soff4[4];
#pragma unroll
  for (int c = 0; c < 4; ++c)
    soff4[c] = ((w & 1) * 64 + c * 16 + (lane >> 2)) * 256 + swz64;
  const char* const asrc = (const char*)((w < 2) ? qi : ki) +
                           (size_t)(((w < 2) ? mtile : ntile) * 128) * 256;
  char* const dbase = smem + ((w < 2) ? 0 : 16384) + (w & 1) * 4096;

#define STG(p, s)                                         \
  do {                                                    \
    const char* _s = asrc + (s) * 64;                     \
    char* _d = dbase + (p) * 8192;                        \
    _Pragma("unroll")                                     \
    for (int c = 0; c < 4; ++c)                           \
      gll16(_s + soff4[c], _d + c * 1024);                \
  } while (0)

  i32x4 acc[4][4];
#pragma unroll
  for (int i = 0; i < 4; i++)
#pragma unroll
    for (int j = 0; j < 4; j++) acc[i][j] = (i32x4){0, 0, 0, 0};

  // ds_read phys chunk: logical chunk q16 -> q16 ^ ((row>>1)&3) = q16^((l16>>1)&3)
  const int pc4 = (q16 ^ ((l16 >> 1) & 3)) * 16;

  STG(0, 0);
  __syncthreads();                       // prologue drain (vmcnt via compiler)
#pragma unroll
  for (int s = 0; s < 4; ++s) {          // 4 K-steps of 64
    if (s < 3) STG((s + 1) & 1, s + 1);  // prefetch next, other buffer
    const int p = (s & 1) * 8192;
    i32x4 av[4], bv[4];
    // A-operand = KEYS (bufB): rows 64*wr + 16*i + l16
#pragma unroll
    for (int i = 0; i < 4; i++)
      av[i] = *(const i32x4*)&smem[16384 + p + (64 * wr + 16 * i + l16) * 64 + pc4];
    // B-operand = QUERIES (bufA): rows 64*wc + 16*j + l16
#pragma unroll
    for (int j = 0; j < 4; j++)
      bv[j] = *(const i32x4*)&smem[p + (64 * wc + 16 * j + l16) * 64 + pc4];
#pragma unroll
    for (int i = 0; i < 4; i++)
#pragma unroll
      for (int j = 0; j < 4; j++)
        acc[i][j] = __builtin_amdgcn_mfma_i32_16x16x64_i8(av[i], bv[j], acc[i][j], 0, 0, 0);
    __syncthreads();                     // drains this wave's stage + LDS reads
  }
#undef STG

  // ---- Epilogue v3: in-register group-max (swapped-operand layout) ----
  // D mapping (m89, dtype-independent): row(key) = 4*q16 + r, col(query) = l16.
  // Lane's key rows: ntile*128 + 64*wr + 16*i + 4*q16 + r.
  float rkv[4][4];
#pragma unroll
  for (int i = 0; i < 4; ++i)
#pragma unroll
    for (int r = 0; r < 4; ++r) {
      const int ncol = ntile * BN + 64 * wr + 16 * i + 4 * q16 + r;
      rkv[i][r] = (ncol < NMEM) ? rkn[ncol] * SS2 : 0.f;  // padded keys -> 0.0
    }
  float (*cg)[128] = (float(*)[128])smem;  // [group 0..7][query 0..127], 4 KB
#pragma unroll
  for (int i = 0; i < 4; ++i) {
#pragma unroll
    for (int j = 0; j < 4; ++j) {
      float m = fmaxf(fmaxf((float)acc[i][j][0] * rkv[i][0],
                            (float)acc[i][j][1] * rkv[i][1]),
                      fmaxf((float)acc[i][j][2] * rkv[i][2],
                            (float)acc[i][j][3] * rkv[i][3]));
      m = fmaxf(m, __shfl_xor(m, 16, 64));   // reduce across q16 groups
      m = fmaxf(m, __shfl_xor(m, 32, 64));
      if (q16 == 0)
        cg[4 * wr + i][64 * wc + 16 * j + l16] = m;   // 16 consecutive floats
    }
  }
  __syncthreads();
  if (t < 128) {
    float v[8];
#pragma unroll
    for (int g = 0; g < 8; ++g) v[g] = cg[g][t];
    const float bm = fmaxf(fmaxf(fmaxf(v[0], v[1]), fmaxf(v[2], v[3])),
                           fmaxf(fmaxf(v[4], v[5]), fmaxf(v[6], v[7])));
    bmaxB[(size_t)ntile * NQ + mtile * 128 + t] = bm;
    unsigned long long cw = 0;
#pragma unroll
    for (int g = 0; g < 8; ++g) {
      int code = (int)((bm - v[g]) * GINVD);     // floor >=0; ub >= gmax always
      code = min(255, max(0, code));
      cw |= (unsigned long long)(unsigned)code << (8 * g);
    }
    bcode8[(size_t)ntile * NQ + mtile * 128 + t] = cw;
  }
}

// bmaxB[782][2048] -> bmaxQ[2048][800] (pad cols 782..799 never read)
__global__ __launch_bounds__(256) void transpose_blk(const float* __restrict__ in,
                                                     float* __restrict__ outp) {
  __shared__ float tl[32][33];
  const int bid = blockIdx.x;
  const int ntt = bid % 25, qt = bid / 25;
  const int r0 = ntt * 32, c0 = qt * 32;
  const int tx = threadIdx.x & 31, ty = threadIdx.x >> 5;   // ty 0..7
#pragma unroll
  for (int k = 0; k < 4; ++k) {
    const int r = r0 + ty + 8 * k;
    tl[ty + 8 * k][tx] = (r < NTILES) ? in[(size_t)r * NQ + c0 + tx] : -FLT_MAX;
  }
  __syncthreads();
#pragma unroll
  for (int k = 0; k < 4; ++k) {
    const int qq = c0 + ty + 8 * k;
    const int nt = r0 + tx;
    if (nt < NTILES) outp[(size_t)qq * BLKPAD + nt] = tl[tx][ty + 8 * k];
  }
}

// Pass 2 per query (1 block), four-level funnel:
//   A)  contiguous bmaxQ scan -> gm, thresh; candidate blocks (~3)
//   B1) decode candidate blocks' u64 group codes: admit group iff
//       bmax - code*GDELTA >= thresh (ub >= gmax always -> truth survives)
//   B2) i8 re-score of candidate groups' 16 rows (bit-identical rounding to
//       the MFMA path) -> row list (~4 rows)
//   C)  exact fp64 cosine for listed rows; argmax, low-index tie-break
// margin 1.8e-2*qn = 14.9 sigma of i8 score error >= 2 x 6.2-sigma bound.
__global__ __launch_bounds__(256) void rescore_gather(
    const float* __restrict__ q, const float* __restrict__ mem,
    const int* __restrict__ qi8, const int* __restrict__ ki8,
    const float* __restrict__ rkn, const float* __restrict__ bmaxQ,
    const unsigned long long* __restrict__ bcode8, float* __restrict__ out) {
  __shared__ float red2[4];
  __shared__ int blist[64];
  __shared__ int nblk;
  __shared__ int glist[128];
  __shared__ int ng;
  __shared__ int rlist[256];
  __shared__ int nrow;
  __shared__ double wb[4];
  __shared__ int wbi[4];
  __shared__ int widx;

  const int qid = blockIdx.x;
  const int t = threadIdx.x, w = t >> 6, lane = t & 63;

  const float4 qv = *(const float4*)&q[(size_t)qid * 256 + lane * 4];
  float ss = qv.x * qv.x + qv.y * qv.y + qv.z * qv.z + qv.w * qv.w;
#pragma unroll
  for (int off = 32; off >= 1; off >>= 1) ss += __shfl_xor(ss, off, 64);
  const float qn = sqrtf(ss);
  const float margin = 1.8e-2f * qn;

  int4 qreg[4];
#pragma unroll
  for (int k = 0; k < 4; ++k)
    qreg[k] = *(const int4*)&qi8[(size_t)qid * 64 + (lane & 3) * 16 + k * 4];

  if (t == 0) { nblk = 0; ng = 0; nrow = 0; }
  const float* bq = &bmaxQ[(size_t)qid * BLKPAD];

  // ---- A ----
  float gm = -FLT_MAX;
  for (int i = t; i < NTILES; i += 256) gm = fmaxf(gm, bq[i]);
#pragma unroll
  for (int off = 32; off >= 1; off >>= 1) gm = fmaxf(gm, __shfl_xor(gm, off, 64));
  if (lane == 0) red2[w] = gm;
  __syncthreads();
  gm = fmaxf(fmaxf(red2[0], red2[1]), fmaxf(red2[2], red2[3]));
  const float thresh = gm - margin;

  for (int i = t; i < NTILES; i += 256)
    if (bq[i] >= thresh) {
      int p = atomicAdd(&nblk, 1);
      if (p < 64) blist[p] = i;
    }
  __syncthreads();
  const int nb_ = min(nblk, 64);

  // ---- B1: decode group codes (u64 broadcast across 8 threads) ----
  for (int idx = t; idx < nb_ * 8; idx += 256) {
    const int nt = blist[idx >> 3], gl = idx & 7;
    const unsigned long long cw = bcode8[(size_t)nt * NQ + qid];
    const int code = (int)((cw >> (8 * gl)) & 255);
    if ((float)code * GDELTA <= bq[nt] - thresh + 1e-6f) {
      int p = atomicAdd(&ng, 1);
      if (p < 128) glist[p] = nt * 8 + gl;   // rows = g*16 + 0..15
    }
  }
  __syncthreads();
  const int ng_ = min(ng, 128);

  // ---- B2: one candidate group per wave pass; 4 lanes per row ----
  for (int c = w; c < ng_; c += 4) {
    const int row = glist[c] * 16 + (lane >> 2);
    int idot = 0;
#pragma unroll
    for (int k = 0; k < 4; ++k) {
      const int4 kv = *(const int4*)&ki8[(size_t)row * 64 + (lane & 3) * 16 + k * 4];
      idot = dot4i8(kv.x, qreg[k].x, idot);
      idot = dot4i8(kv.y, qreg[k].y, idot);
      idot = dot4i8(kv.z, qreg[k].z, idot);
      idot = dot4i8(kv.w, qreg[k].w, idot);
    }
    idot += __shfl_xor(idot, 1, 64);
    idot += __shfl_xor(idot, 2, 64);
    if ((lane & 3) == 0 && row < NMEM) {
      const float sh = (float)idot * (rkn[row] * SS2);  // == gemm's value, bit-exact
      if (sh >= thresh) {
        int p = atomicAdd(&nrow, 1);
        if (p < 256) rlist[p] = row;
      }
    }
  }
  __syncthreads();
  const int nr = min(nrow, 256);

  // ---- C ----
  double bestv = -1e300;
  int bestidx = 0x7fffffff;
  for (int c = w; c < nr; c += 4) {
    const int row = rlist[c];
    const float4 kv = *(const float4*)&mem[(size_t)row * 512 + lane * 4];
    double d = (double)kv.x * qv.x + (double)kv.y * qv.y +
               (double)kv.z * qv.z + (double)kv.w * qv.w;
    double s2 = (double)kv.x * kv.x + (double)kv.y * kv.y +
                (double)kv.z * kv.z + (double)kv.w * kv.w;
#pragma unroll
    for (int off = 32; off >= 1; off >>= 1) {
      d += __shfl_xor(d, off, 64);
      s2 += __shfl_xor(s2, off, 64);
    }
    if (lane == 0) {
      const double score = d / sqrt(s2 > 1e-300 ? s2 : 1e-300);
      if (score > bestv || (score == bestv && row < bestidx)) {
        bestv = score;
        bestidx = row;
      }
    }
  }
  if (lane == 0) { wb[w] = bestv; wbi[w] = bestidx; }
  __syncthreads();
  if (t == 0) {
    double bv = wb[0];
    int bi = wbi[0];
#pragma unroll
    for (int w2 = 1; w2 < 4; ++w2)
      if (wb[w2] > bv || (wb[w2] == bv && wbi[w2] < bi)) {
        bv = wb[w2];
        bi = wbi[w2];
      }
    widx = bi;
  }
  __syncthreads();
  out[(size_t)qid * 256 + t] = mem[(size_t)widx * 512 + 256 + t];
}

extern "C" void kernel_launch(void* const* d_in, const int* in_sizes, int n_in,
                              void* d_out, int out_size, void* d_ws, size_t ws_size,
                              hipStream_t stream) {
  const float* query = (const float*)d_in[0];
  const float* memory = (const float*)d_in[1];
  float* out = (float*)d_out;

  char* p = (char*)d_ws;
  int* qi = (int*)p; p += (size_t)NQ * 64 * 4;               // 2 MB
  int* ki = (int*)p; p += (size_t)NPAD * 64 * 4;             // 25.6 MB
  float* rkn = (float*)p; p += (size_t)NPAD * 4;             // 0.4 MB
  float* bmaxB = (float*)p; p += (size_t)NTILES * NQ * 4;    // 6.4 MB
  float* bmaxQ = (float*)p; p += (size_t)NQ * BLKPAD * 4;    // 6.6 MB
  unsigned long long* bcode8 = (unsigned long long*)p;
  p += (size_t)NTILES * NQ * 8;                              // 12.8 MB

  hipLaunchKernelGGL(convert, dim3(KB16 + NQ * MKEY / 1024), dim3(256), 0, stream,
                     query, memory, qi, ki, rkn);
  hipLaunchKernelGGL(gemm_screen, dim3(GRID), dim3(256), 0, stream,
                     qi, ki, rkn, bcode8, bmaxB);
  hipLaunchKernelGGL(transpose_blk, dim3(25 * 64), dim3(256), 0, stream, bmaxB, bmaxQ);
  hipLaunchKernelGGL(rescore_gather, dim3(NQ), dim3(256), 0, stream,
                     query, memory, qi, ki, rkn, bmaxQ, bcode8, out);
}